// Round 2
// baseline (210.352 us; speedup 1.0000x reference)
//
#include <hip/hip_runtime.h>

// MultiScaleRoIAlign: B=2, C=256, L=256 rois/img -> K=512
// feats: (2,256,200,200) s=1/4, (2,256,100,100) s=1/8, (2,256,50,50) s=1/16, (2,256,25,25) s=1/32
// out: (K, C, 7, 7) fp32
// SR=2 subsamples per bin axis, bilinear, avg over 4 subsamples.

#define OUT_HW 7
#define KROIS 512
#define NCH 256
#define LPB 256  // rois per batch image

__global__ __launch_bounds__(256) void msroi_kernel(
    const float* __restrict__ f0, const float* __restrict__ f1,
    const float* __restrict__ f2, const float* __restrict__ f3,
    const float* __restrict__ boxes, float* __restrict__ out, int total)
{
    int idx = blockIdx.x * blockDim.x + threadIdx.x;
    if (idx >= total) return;

    int pw = idx % OUT_HW;
    int ph = (idx / OUT_HW) % OUT_HW;
    int c  = (idx / (OUT_HW * OUT_HW)) % NCH;
    int k  = idx / (OUT_HW * OUT_HW * NCH);
    int b  = k / LPB;  // batch index

    // ROI box
    float bx1 = boxes[k * 4 + 0];
    float by1 = boxes[k * 4 + 1];
    float bx2 = boxes[k * 4 + 2];
    float by2 = boxes[k * 4 + 3];

    // level assignment: floor(4 + log2(sqrt(area)/224) + 1e-6), clip [2,5], -2
    float area = (bx2 - bx1) * (by2 - by1);
    float s = sqrtf(area);
    float lvlf = floorf(4.0f + log2f(s * (1.0f / 224.0f)) + 1e-6f);
    lvlf = fminf(fmaxf(lvlf, 2.0f), 5.0f);
    int lvl = (int)lvlf - 2;

    const float* feat;
    int H, W;
    float scale;
    if (lvl == 0)      { feat = f0; H = 200; W = 200; scale = 0.25f;    }
    else if (lvl == 1) { feat = f1; H = 100; W = 100; scale = 0.125f;   }
    else if (lvl == 2) { feat = f2; H = 50;  W = 50;  scale = 0.0625f;  }
    else               { feat = f3; H = 25;  W = 25;  scale = 0.03125f; }

    float x1 = bx1 * scale;
    float y1 = by1 * scale;
    float x2 = bx2 * scale;
    float y2 = by2 * scale;
    float roi_w = fmaxf(x2 - x1, 1.0f);
    float roi_h = fmaxf(y2 - y1, 1.0f);
    float bin_h = roi_h * (1.0f / OUT_HW);
    float bin_w = roi_w * (1.0f / OUT_HW);

    const float* base = feat + ((size_t)b * NCH + c) * (size_t)(H * W);

    float acc = 0.0f;
#pragma unroll
    for (int iy = 0; iy < 2; ++iy) {
        float y = y1 + ph * bin_h + (iy + 0.5f) * (bin_h * 0.5f);
        y = fmaxf(y, 0.0f);
        int ylo = (int)y;               // trunc == floor since y >= 0
        int yhi;
        if (ylo >= H - 1) { ylo = H - 1; yhi = H - 1; }
        else              { yhi = ylo + 1; }
        float ly = y - (float)ylo;
        float hy = 1.0f - ly;
#pragma unroll
        for (int ix = 0; ix < 2; ++ix) {
            float x = x1 + pw * bin_w + (ix + 0.5f) * (bin_w * 0.5f);
            x = fmaxf(x, 0.0f);
            int xlo = (int)x;
            int xhi;
            if (xlo >= W - 1) { xlo = W - 1; xhi = W - 1; }
            else              { xhi = xlo + 1; }
            float lx = x - (float)xlo;
            float hx = 1.0f - lx;

            float v00 = base[ylo * W + xlo];
            float v01 = base[ylo * W + xhi];
            float v10 = base[yhi * W + xlo];
            float v11 = base[yhi * W + xhi];

            acc += hy * hx * v00 + hy * lx * v01 + ly * hx * v10 + ly * lx * v11;
        }
    }
    out[idx] = acc * 0.25f;
}

extern "C" void kernel_launch(void* const* d_in, const int* in_sizes, int n_in,
                              void* d_out, int out_size, void* d_ws, size_t ws_size,
                              hipStream_t stream)
{
    const float* f0 = (const float*)d_in[0];
    const float* f1 = (const float*)d_in[1];
    const float* f2 = (const float*)d_in[2];
    const float* f3 = (const float*)d_in[3];
    const float* boxes = (const float*)d_in[4];
    float* out = (float*)d_out;

    int total = KROIS * NCH * OUT_HW * OUT_HW;  // 6,422,528
    int block = 256;
    int grid = (total + block - 1) / block;
    msroi_kernel<<<grid, block, 0, stream>>>(f0, f1, f2, f3, boxes, out, total);
}